// Round 1
// baseline (5332.452 us; speedup 1.0000x reference)
//
#include <hip/hip_runtime.h>

// ============================================================================
// VRNN_DAT_4655744548920  — round 1
//
// Architecture:
//   Phase 0: pack all weights to fp16 blobs in ws (GEMV layout [kc][col][8]
//            for the recurrent loop; transposed [n][k] for MFMA B-frags).
//   Phase 1: phi_x chain batched over all B*T rows (x-only dependence).
//   Phase 2: persistent recurrent kernel. 128 blocks x 512 threads, block b
//            owns batch rows 2b, 2b+1 for all T=512 steps. Only the
//            enc1->enc2->heads->z->phi_z->GRU chain runs in-loop (dot2 fp16,
//            fp32 accum, fp32 recurrent state). Streams weights from L2.
//            Stores carry h_{t-1} and phi_z_t as fp16 for phase 3.
//   Phase 3: deferred prior & decoder paths as batched MFMA GEMMs (M=131072).
//
// Round-2 TODO: weight residency (LDS>64KB probe + register pinning) to cut
// the ~875KB/step L2 stream; merge barriers; use idle 128 CUs.
// ============================================================================

typedef _Float16 f16;
typedef _Float16 f16x2 __attribute__((ext_vector_type(2)));
typedef _Float16 f16x8 __attribute__((ext_vector_type(8)));
typedef float    f32x4 __attribute__((ext_vector_type(4)));

#define B_  256
#define T_  512
#define BT_ 131072

// d_out offsets (elements, fp32)
#define OYP   0u
#define OPHIX 8388608u
#define OENCM 12582912u
#define OENCS 20971520u
#define ODECM 29360128u
#define ODECS 37748736u
#define OPRIM 46137344u
#define OPRIS 54525952u

// ws offsets (bytes)
#define WS_PHIX16 0ull
#define WS_H16    8388608ull
#define WS_PZ16   75497472ull
#define WS_WHB    92274688ull   // [32][1024][8] fp16  (enc_W1_bot | gru_R)
#define WS_W1TOP  92798976ull   // [4][256][8]
#define WS_KTOP   92815360ull   // [4][768][8]
#define WS_KBOT   92864512ull   // [8][768][8]
#define WS_ENCW2  92962816ull   // [32][256][8]
#define WS_HEADS  93093888ull   // [32][128][8]   (enc_mean_W | enc_std_W)
#define WS_PHIZW  93159424ull   // [8][64][8]
#define WS_DECW1T 93167616ull   // [256][320]
#define WS_DECW2T 93331456ull   // [256][256]
#define WS_DECHT  93462528ull   // [128][256]
#define WS_PRIWT  93528064ull   // [256][256]
#define WS_PRIHT  93659136ull   // [128][256]

#if defined(__has_builtin)
#if __has_builtin(__builtin_amdgcn_fdot2)
#define HAVE_FDOT2 1
#endif
#endif

__device__ __forceinline__ float dot8(uint4 w, uint4 h, float acc) {
#ifdef HAVE_FDOT2
    union { uint4 u; f16x2 p[4]; } a, b;
    a.u = w; b.u = h;
    acc = __builtin_amdgcn_fdot2(a.p[0], b.p[0], acc, false);
    acc = __builtin_amdgcn_fdot2(a.p[1], b.p[1], acc, false);
    acc = __builtin_amdgcn_fdot2(a.p[2], b.p[2], acc, false);
    acc = __builtin_amdgcn_fdot2(a.p[3], b.p[3], acc, false);
#else
    union { uint4 u; f16 h8[8]; } a, b;
    a.u = w; b.u = h;
#pragma unroll
    for (int i = 0; i < 8; ++i) acc += (float)a.h8[i] * (float)b.h8[i];
#endif
    return acc;
}

__device__ __forceinline__ float softplus_f(float v) {
    // stable log1p(exp(v))
    return (v > 15.f) ? v : log1pf(expf(v));
}
__device__ __forceinline__ float sigmoid_f(float v) {
    return 1.f / (1.f + expf(-v));
}

// ---------------------------------------------------------------------------
// Phase 0: weight packing
// ---------------------------------------------------------------------------
__global__ void pack_loop(const float* __restrict__ src, f16* __restrict__ dst,
                          int K, int Nsrc, int Ndst, int coloff) {
    int idx = blockIdx.x * 256 + threadIdx.x;
    if (idx >= K * Nsrc) return;
    int k = idx / Nsrc, j = idx - k * Nsrc;
    dst[((size_t)(k >> 3) * Ndst + coloff + j) * 8 + (k & 7)] = (f16)src[idx];
}

__global__ void pack_T(const float* __restrict__ src, f16* __restrict__ dst,
                       int K, int N, int noff, int Kd) {
    int idx = blockIdx.x * 256 + threadIdx.x;
    if (idx >= K * N) return;
    int k = idx / N, n = idx - k * N;
    dst[(size_t)(noff + n) * Kd + k] = (f16)src[idx];
}

// ---------------------------------------------------------------------------
// Phase 1: phi_x for all B*T rows. One thread per row.
// ---------------------------------------------------------------------------
__global__ void phi_x_kernel(const float* __restrict__ x,
                             const float* __restrict__ W1, const float* __restrict__ b1,
                             const float* __restrict__ W2, const float* __restrict__ b2,
                             float* __restrict__ dout, f16* __restrict__ phix16) {
    size_t row = (size_t)blockIdx.x * 256 + threadIdx.x;
    const float* xr = x + row * 64;
    float l1[32];
#pragma unroll
    for (int j = 0; j < 32; ++j) l1[j] = b1[j];
#pragma unroll 4
    for (int k = 0; k < 64; ++k) {
        float xv = xr[k];
#pragma unroll
        for (int j = 0; j < 32; ++j) l1[j] += xv * W1[k * 32 + j];
    }
#pragma unroll
    for (int j = 0; j < 32; ++j) l1[j] = fmaxf(l1[j], 0.f);
#pragma unroll 4
    for (int j = 0; j < 32; ++j) {
        float acc = b2[j];
#pragma unroll
        for (int k = 0; k < 32; ++k) acc += l1[k] * W2[k * 32 + j];
        acc = fmaxf(acc, 0.f);
        dout[OPHIX + row * 32 + j] = acc;
        phix16[row * 32 + j] = (f16)acc;
    }
}

// ---------------------------------------------------------------------------
// Phase 2: recurrent loop. 128 blocks x 512 threads; block b owns rows 2b,2b+1.
// ---------------------------------------------------------------------------
__launch_bounds__(512)
__global__ void vrnn_recurrent(
    const f16* __restrict__ whb,     // [32][1024][8]: cols 0..255 enc_W1_bot, 256..1023 gru_R
    const f16* __restrict__ w1topb,  // [4][256][8]
    const f16* __restrict__ ktopb,   // [4][768][8]
    const f16* __restrict__ kbotb,   // [8][768][8]
    const f16* __restrict__ encw2b,  // [32][256][8]
    const f16* __restrict__ headsb,  // [32][128][8]
    const f16* __restrict__ phizwb,  // [8][64][8]
    const float* __restrict__ enc_b1, const float* __restrict__ enc_b2,
    const float* __restrict__ enc_mean_b, const float* __restrict__ enc_std_b,
    const float* __restrict__ phi_z_b, const float* __restrict__ gru_b,
    const f16* __restrict__ phix16, const float* __restrict__ eps,
    f16* __restrict__ h16, f16* __restrict__ pz16, float* __restrict__ dout) {

    const int tid = threadIdx.x;
    const int r0 = blockIdx.x * 2;

    __shared__ __align__(16) f16 h_sh[2][256];
    __shared__ __align__(16) f16 e1s[2][256];
    __shared__ __align__(16) f16 ehs[2][256];
    __shared__ __align__(16) f16 zps[2][64];
    __shared__ __align__(16) f16 pzs[2][64];
    __shared__ __align__(16) f16 phixs[2][32];
    __shared__ float hf[2][256];
    __shared__ float hs[2][768];
    __shared__ float xsm[2][768];
    __shared__ float ps[1024];
    __shared__ float sb_e1[256], sb_e2[256], sb_hm[128], sb_pz[64];
    __shared__ float sb_bk[768], sb_br[768];

    // biases -> LDS; zero recurrent state
    if (tid < 256) {
        sb_e1[tid] = enc_b1[tid];
        sb_e2[tid] = enc_b2[tid];
        h_sh[0][tid] = (f16)0.f; h_sh[1][tid] = (f16)0.f;
        hf[0][tid] = 0.f; hf[1][tid] = 0.f;
    }
    if (tid < 128) sb_hm[tid] = (tid < 64) ? enc_mean_b[tid] : enc_std_b[tid - 64];
    if (tid < 64)  sb_pz[tid] = phi_z_b[tid];
    { int i = tid; if (i < 768) { sb_bk[i] = gru_b[i]; sb_br[i] = gru_b[768 + i]; } }
    if (tid >= 256) { int i = tid - 256 + 512; if (i < 768) { sb_bk[i] = gru_b[i]; sb_br[i] = gru_b[768 + i]; } }
    // phix[t=0]
    if (tid < 32) {
        int r = tid >> 4, d = tid & 15;
        ((unsigned int*)phixs[r])[d] =
            ((const unsigned int*)(phix16 + (size_t)(r0 + r) * T_ * 32))[d];
    }
    float eps_reg = 0.f;
    if (tid < 128) {
        int r = tid >> 6, c = tid & 63;
        eps_reg = eps[((size_t)(r0 + r) * T_) * 64 + c];
    }
    __syncthreads();

    const int mA = (tid >= 256) ? (tid - 256) : -1;  // mh/mx col A
    const int mB = 256 + tid;                        // mh/mx col B

    const uint4* whu   = (const uint4*)whb;
    const uint4* w1tu  = (const uint4*)w1topb;
    const uint4* ktu   = (const uint4*)ktopb;
    const uint4* kbu   = (const uint4*)kbotb;
    const uint4* ew2u  = (const uint4*)encw2b;
    const uint4* hdu   = (const uint4*)headsb;
    const uint4* pzwu  = (const uint4*)phizwb;

    for (int t = 0; t < T_; ++t) {
        // ---- S1: Wh = h @ [enc_W1_bot | gru_R]  (+ W1top, K_top from phi_x)
        float a0, a1, b0, b1;
        if (tid < 256) { a0 = sb_e1[tid]; } else { a0 = sb_br[tid - 256]; }
        a1 = a0;
        b0 = sb_br[mB]; b1 = b0;
        const uint4* h0p = (const uint4*)h_sh[0];
        const uint4* h1p = (const uint4*)h_sh[1];
#pragma unroll 4
        for (int kc = 0; kc < 32; ++kc) {
            uint4 hv0 = h0p[kc], hv1 = h1p[kc];
            uint4 wa = whu[kc * 1024 + tid];
            uint4 wb = whu[kc * 1024 + 512 + tid];
            a0 = dot8(wa, hv0, a0); a1 = dot8(wa, hv1, a1);
            b0 = dot8(wb, hv0, b0); b1 = dot8(wb, hv1, b1);
        }
        // K_top -> mx accumulators (live until S7)
        float xA0 = 0.f, xA1 = 0.f, xB0, xB1;
        xB0 = sb_bk[mB]; xB1 = xB0;
        if (mA >= 0) { xA0 = sb_bk[mA]; xA1 = xA0; }
        const uint4* px0p = (const uint4*)phixs[0];
        const uint4* px1p = (const uint4*)phixs[1];
#pragma unroll
        for (int kc = 0; kc < 4; ++kc) {
            uint4 p0 = px0p[kc], p1 = px1p[kc];
            uint4 wB = ktu[kc * 768 + mB];
            xB0 = dot8(wB, p0, xB0); xB1 = dot8(wB, p1, xB1);
            if (mA >= 0) {
                uint4 wA = ktu[kc * 768 + mA];
                xA0 = dot8(wA, p0, xA0); xA1 = dot8(wA, p1, xA1);
            }
        }
        if (tid < 256) {
#pragma unroll
            for (int kc = 0; kc < 4; ++kc) {
                uint4 p0 = px0p[kc], p1 = px1p[kc];
                uint4 w = w1tu[kc * 256 + tid];
                a0 = dot8(w, p0, a0); a1 = dot8(w, p1, a1);
            }
            e1s[0][tid] = (f16)fmaxf(a0, 0.f);
            e1s[1][tid] = (f16)fmaxf(a1, 0.f);
        } else {
            hs[0][tid - 256] = a0; hs[1][tid - 256] = a1;
        }
        hs[0][mB] = b0; hs[1][mB] = b1;
        __syncthreads();

        // ---- S4: enc2 (k-split by 2)
        {
            int c = tid & 255, kh = tid >> 8;
            float p0 = 0.f, p1 = 0.f;
            const uint4* e0p = (const uint4*)e1s[0];
            const uint4* e1p = (const uint4*)e1s[1];
#pragma unroll 4
            for (int i = 0; i < 16; ++i) {
                int kc = kh * 16 + i;
                uint4 w = ew2u[kc * 256 + c];
                p0 = dot8(w, e0p[kc], p0);
                p1 = dot8(w, e1p[kc], p1);
            }
            ps[(0 * 2 + kh) * 256 + c] = p0;
            ps[(2 + kh) * 256 + c] = p1;
        }
        __syncthreads();
        {
            int r = tid >> 8, j = tid & 255;
            float v = ps[(r * 2) * 256 + j] + ps[(r * 2 + 1) * 256 + j] + sb_e2[j];
            ehs[r][j] = (f16)fmaxf(v, 0.f);
        }
        __syncthreads();

        // ---- S5: enc heads (mean|std), k-split by 4
        {
            int c2 = tid & 127, kq = tid >> 7;
            float p0 = 0.f, p1 = 0.f;
            const uint4* h0e = (const uint4*)ehs[0];
            const uint4* h1e = (const uint4*)ehs[1];
#pragma unroll 4
            for (int i = 0; i < 8; ++i) {
                int kc = kq * 8 + i;
                uint4 w = hdu[kc * 128 + c2];
                p0 = dot8(w, h0e[kc], p0);
                p1 = dot8(w, h1e[kc], p1);
            }
            ps[kq * 128 + c2] = p0;
            ps[(4 + kq) * 128 + c2] = p1;
        }
        __syncthreads();
        if (tid < 128) {
            int r = tid >> 6, c = tid & 63;
            float m = sb_hm[c], s = sb_hm[64 + c];
#pragma unroll
            for (int kq = 0; kq < 4; ++kq) {
                m += ps[(r * 4 + kq) * 128 + c];
                s += ps[(r * 4 + kq) * 128 + 64 + c];
            }
            float sp = softplus_f(s);
            float z = eps_reg * sp + m;
            size_t bt = (size_t)(r0 + r) * T_ + t;
            dout[OENCM + bt * 64 + c] = m;
            dout[OENCS + bt * 64 + c] = sp;
            dout[OYP + bt * 64 + c] = z;
            zps[r][c] = (f16)z;
        }
        __syncthreads();

        // ---- S6: phi_z (k-split by 8)
        {
            int c = tid & 63, k8 = tid >> 6;
            uint4 w = pzwu[k8 * 64 + c];
            ps[k8 * 64 + c]       = dot8(w, ((const uint4*)zps[0])[k8], 0.f);
            ps[(8 + k8) * 64 + c] = dot8(w, ((const uint4*)zps[1])[k8], 0.f);
        }
        __syncthreads();
        if (tid < 128) {
            int r = tid >> 6, c = tid & 63;
            float v = sb_pz[c];
#pragma unroll
            for (int k = 0; k < 8; ++k) v += ps[(r * 8 + k) * 64 + c];
            v = fmaxf(v, 0.f);
            pzs[r][c] = (f16)v;
            size_t bt = (size_t)(r0 + r) * T_ + t;
            pz16[bt * 64 + c] = (f16)v;
            if (t + 1 < T_)  // eps prefetch for next step
                eps_reg = eps[((size_t)(r0 + r) * T_ + (t + 1)) * 64 + c];
        } else if (tid < 160 && (t + 1 < T_)) {  // phix prefetch
            int r = (tid - 128) >> 4, d = (tid - 128) & 15;
            ((unsigned int*)phixs[r])[d] =
                ((const unsigned int*)(phix16 + ((size_t)(r0 + r) * T_ + (t + 1)) * 32))[d];
        }
        __syncthreads();

        // ---- S7: K_bot (phi_z part of mx)
        {
            const uint4* p0p = (const uint4*)pzs[0];
            const uint4* p1p = (const uint4*)pzs[1];
#pragma unroll
            for (int kc = 0; kc < 8; ++kc) {
                uint4 p0 = p0p[kc], p1 = p1p[kc];
                uint4 wB = kbu[kc * 768 + mB];
                xB0 = dot8(wB, p0, xB0); xB1 = dot8(wB, p1, xB1);
                if (mA >= 0) {
                    uint4 wA = kbu[kc * 768 + mA];
                    xA0 = dot8(wA, p0, xA0); xA1 = dot8(wA, p1, xA1);
                }
            }
            xsm[0][mB] = xB0; xsm[1][mB] = xB1;
            if (mA >= 0) { xsm[0][mA] = xA0; xsm[1][mA] = xA1; }
        }
        __syncthreads();

        // ---- S8: GRU gates + state update; store CARRY h_{t-1} for phase 3
        {
            int g = tid & 255, r = tid >> 8;
            float zg = sigmoid_f(xsm[r][g] + hs[r][g]);
            float rg = sigmoid_f(xsm[r][256 + g] + hs[r][256 + g]);
            float hc = tanhf(xsm[r][512 + g] + rg * hs[r][512 + g]);
            float hp = hf[r][g];
            float hn = zg * hp + (1.f - zg) * hc;
            hf[r][g] = hn;
            h_sh[r][g] = (f16)hn;
            size_t bt = (size_t)(r0 + r) * T_ + t;
            h16[bt * 256 + g] = (f16)hp;  // carry (h_{t-1}) -> dec/prior inputs
        }
        __syncthreads();
    }
}

// ---------------------------------------------------------------------------
// Phase 3: deferred decoder / prior via MFMA (M-tile = 32, 4 waves)
// A-frag: A[m=lane&15][k=(lane>>4)*8+j]; B-frag: B[k=(lane>>4)*8+j][n=lane&15];
// C/D: col=lane&15, row=(lane>>4)*4+reg   (m89/m101/m120-verified layouts)
// ---------------------------------------------------------------------------
__launch_bounds__(256)
__global__ void dec_kernel(const f16* __restrict__ h16, const f16* __restrict__ pz16,
                           const f16* __restrict__ w1T, const f16* __restrict__ w2T,
                           const f16* __restrict__ hT,
                           const float* __restrict__ b1, const float* __restrict__ b2,
                           const float* __restrict__ bm, const float* __restrict__ bs,
                           float* __restrict__ dout) {
    __shared__ __align__(16) f16 ht[32][264];
    __shared__ __align__(16) f16 pzt[32][72];
    __shared__ __align__(16) f16 d1[32][264];
    __shared__ __align__(16) f16 d2[32][264];
    const int tid = threadIdx.x;
    const size_t bt0 = (size_t)blockIdx.x * 32;

    {   // stage A tiles
        int row = tid >> 3, p = tid & 7;
        const uint4* src = (const uint4*)(h16 + (bt0 + row) * 256);
#pragma unroll
        for (int i = 0; i < 4; ++i)
            *(uint4*)&ht[row][(p * 4 + i) * 8] = src[p * 4 + i];
        const uint4* s2 = (const uint4*)(pz16 + (bt0 + row) * 64);
        *(uint4*)&pzt[row][p * 8] = s2[p];
    }
    __syncthreads();

    const int w = tid >> 6, lane = tid & 63;
    const int lm = lane & 15, lk = (lane >> 4) * 8, lr = (lane >> 4) * 4;
    const int n0 = w * 64;

    f32x4 acc[2][4];
#pragma unroll
    for (int ms = 0; ms < 2; ++ms)
#pragma unroll
        for (int ns = 0; ns < 4; ++ns) acc[ms][ns] = (f32x4){0.f, 0.f, 0.f, 0.f};

    // dec1: K=64 (phi_z) + K=256 (h)
#pragma unroll
    for (int kc = 0; kc < 2; ++kc) {
        f16x8 A[2];
#pragma unroll
        for (int ms = 0; ms < 2; ++ms) A[ms] = *(const f16x8*)&pzt[ms * 16 + lm][kc * 32 + lk];
#pragma unroll
        for (int ns = 0; ns < 4; ++ns) {
            f16x8 Bf = *(const f16x8*)(w1T + (size_t)(n0 + ns * 16 + lm) * 320 + kc * 32 + lk);
#pragma unroll
            for (int ms = 0; ms < 2; ++ms)
                acc[ms][ns] = __builtin_amdgcn_mfma_f32_16x16x32_f16(A[ms], Bf, acc[ms][ns], 0, 0, 0);
        }
    }
#pragma unroll 2
    for (int kc = 0; kc < 8; ++kc) {
        f16x8 A[2];
#pragma unroll
        for (int ms = 0; ms < 2; ++ms) A[ms] = *(const f16x8*)&ht[ms * 16 + lm][kc * 32 + lk];
#pragma unroll
        for (int ns = 0; ns < 4; ++ns) {
            f16x8 Bf = *(const f16x8*)(w1T + (size_t)(n0 + ns * 16 + lm) * 320 + 64 + kc * 32 + lk);
#pragma unroll
            for (int ms = 0; ms < 2; ++ms)
                acc[ms][ns] = __builtin_amdgcn_mfma_f32_16x16x32_f16(A[ms], Bf, acc[ms][ns], 0, 0, 0);
        }
    }
#pragma unroll
    for (int ns = 0; ns < 4; ++ns) {
        float bv = b1[n0 + ns * 16 + lm];
#pragma unroll
        for (int ms = 0; ms < 2; ++ms)
#pragma unroll
            for (int q = 0; q < 4; ++q)
                d1[ms * 16 + lr + q][n0 + ns * 16 + lm] = (f16)fmaxf(acc[ms][ns][q] + bv, 0.f);
    }
    __syncthreads();

    // dec2: K=256
#pragma unroll
    for (int ms = 0; ms < 2; ++ms)
#pragma unroll
        for (int ns = 0; ns < 4; ++ns) acc[ms][ns] = (f32x4){0.f, 0.f, 0.f, 0.f};
#pragma unroll 2
    for (int kc = 0; kc < 8; ++kc) {
        f16x8 A[2];
#pragma unroll
        for (int ms = 0; ms < 2; ++ms) A[ms] = *(const f16x8*)&d1[ms * 16 + lm][kc * 32 + lk];
#pragma unroll
        for (int ns = 0; ns < 4; ++ns) {
            f16x8 Bf = *(const f16x8*)(w2T + (size_t)(n0 + ns * 16 + lm) * 256 + kc * 32 + lk);
#pragma unroll
            for (int ms = 0; ms < 2; ++ms)
                acc[ms][ns] = __builtin_amdgcn_mfma_f32_16x16x32_f16(A[ms], Bf, acc[ms][ns], 0, 0, 0);
        }
    }
#pragma unroll
    for (int ns = 0; ns < 4; ++ns) {
        float bv = b2[n0 + ns * 16 + lm];
#pragma unroll
        for (int ms = 0; ms < 2; ++ms)
#pragma unroll
            for (int q = 0; q < 4; ++q)
                d2[ms * 16 + lr + q][n0 + ns * 16 + lm] = (f16)fmaxf(acc[ms][ns][q] + bv, 0.f);
    }
    __syncthreads();

    // heads: N=128 on waves 0,1
    if (w < 2) {
        const int n0h = w * 64;
#pragma unroll
        for (int ms = 0; ms < 2; ++ms)
#pragma unroll
            for (int ns = 0; ns < 4; ++ns) acc[ms][ns] = (f32x4){0.f, 0.f, 0.f, 0.f};
#pragma unroll 2
        for (int kc = 0; kc < 8; ++kc) {
            f16x8 A[2];
#pragma unroll
            for (int ms = 0; ms < 2; ++ms) A[ms] = *(const f16x8*)&d2[ms * 16 + lm][kc * 32 + lk];
#pragma unroll
            for (int ns = 0; ns < 4; ++ns) {
                f16x8 Bf = *(const f16x8*)(hT + (size_t)(n0h + ns * 16 + lm) * 256 + kc * 32 + lk);
#pragma unroll
                for (int ms = 0; ms < 2; ++ms)
                    acc[ms][ns] = __builtin_amdgcn_mfma_f32_16x16x32_f16(A[ms], Bf, acc[ms][ns], 0, 0, 0);
            }
        }
#pragma unroll
        for (int ns = 0; ns < 4; ++ns) {
            int n = n0h + ns * 16 + lm;
#pragma unroll
            for (int ms = 0; ms < 2; ++ms)
#pragma unroll
                for (int q = 0; q < 4; ++q) {
                    size_t bt = bt0 + ms * 16 + lr + q;
                    float v = acc[ms][ns][q];
                    if (n < 64) dout[ODECM + bt * 64 + n] = v + bm[n];
                    else        dout[ODECS + bt * 64 + (n - 64)] = softplus_f(v + bs[n - 64]);
                }
        }
    }
}

__launch_bounds__(256)
__global__ void pri_kernel(const f16* __restrict__ h16,
                           const f16* __restrict__ wT, const f16* __restrict__ hT,
                           const float* __restrict__ b1,
                           const float* __restrict__ bm, const float* __restrict__ bs,
                           float* __restrict__ dout) {
    __shared__ __align__(16) f16 ht[32][264];
    __shared__ __align__(16) f16 p1[32][264];
    const int tid = threadIdx.x;
    const size_t bt0 = (size_t)blockIdx.x * 32;
    {
        int row = tid >> 3, p = tid & 7;
        const uint4* src = (const uint4*)(h16 + (bt0 + row) * 256);
#pragma unroll
        for (int i = 0; i < 4; ++i)
            *(uint4*)&ht[row][(p * 4 + i) * 8] = src[p * 4 + i];
    }
    __syncthreads();
    const int w = tid >> 6, lane = tid & 63;
    const int lm = lane & 15, lk = (lane >> 4) * 8, lr = (lane >> 4) * 4;
    const int n0 = w * 64;

    f32x4 acc[2][4];
#pragma unroll
    for (int ms = 0; ms < 2; ++ms)
#pragma unroll
        for (int ns = 0; ns < 4; ++ns) acc[ms][ns] = (f32x4){0.f, 0.f, 0.f, 0.f};
#pragma unroll 2
    for (int kc = 0; kc < 8; ++kc) {
        f16x8 A[2];
#pragma unroll
        for (int ms = 0; ms < 2; ++ms) A[ms] = *(const f16x8*)&ht[ms * 16 + lm][kc * 32 + lk];
#pragma unroll
        for (int ns = 0; ns < 4; ++ns) {
            f16x8 Bf = *(const f16x8*)(wT + (size_t)(n0 + ns * 16 + lm) * 256 + kc * 32 + lk);
#pragma unroll
            for (int ms = 0; ms < 2; ++ms)
                acc[ms][ns] = __builtin_amdgcn_mfma_f32_16x16x32_f16(A[ms], Bf, acc[ms][ns], 0, 0, 0);
        }
    }
#pragma unroll
    for (int ns = 0; ns < 4; ++ns) {
        float bv = b1[n0 + ns * 16 + lm];
#pragma unroll
        for (int ms = 0; ms < 2; ++ms)
#pragma unroll
            for (int q = 0; q < 4; ++q)
                p1[ms * 16 + lr + q][n0 + ns * 16 + lm] = (f16)fmaxf(acc[ms][ns][q] + bv, 0.f);
    }
    __syncthreads();
    if (w < 2) {
        const int n0h = w * 64;
#pragma unroll
        for (int ms = 0; ms < 2; ++ms)
#pragma unroll
            for (int ns = 0; ns < 4; ++ns) acc[ms][ns] = (f32x4){0.f, 0.f, 0.f, 0.f};
#pragma unroll 2
        for (int kc = 0; kc < 8; ++kc) {
            f16x8 A[2];
#pragma unroll
            for (int ms = 0; ms < 2; ++ms) A[ms] = *(const f16x8*)&p1[ms * 16 + lm][kc * 32 + lk];
#pragma unroll
            for (int ns = 0; ns < 4; ++ns) {
                f16x8 Bf = *(const f16x8*)(hT + (size_t)(n0h + ns * 16 + lm) * 256 + kc * 32 + lk);
#pragma unroll
                for (int ms = 0; ms < 2; ++ms)
                    acc[ms][ns] = __builtin_amdgcn_mfma_f32_16x16x32_f16(A[ms], Bf, acc[ms][ns], 0, 0, 0);
            }
        }
#pragma unroll
        for (int ns = 0; ns < 4; ++ns) {
            int n = n0h + ns * 16 + lm;
#pragma unroll
            for (int ms = 0; ms < 2; ++ms)
#pragma unroll
                for (int q = 0; q < 4; ++q) {
                    size_t bt = bt0 + ms * 16 + lr + q;
                    float v = acc[ms][ns][q];
                    if (n < 64) dout[OPRIM + bt * 64 + n] = v + bm[n];
                    else        dout[OPRIS + bt * 64 + (n - 64)] = softplus_f(v + bs[n - 64]);
                }
        }
    }
}

// ---------------------------------------------------------------------------
extern "C" void kernel_launch(void* const* d_in, const int* in_sizes, int n_in,
                              void* d_out, int out_size, void* d_ws, size_t ws_size,
                              hipStream_t stream) {
    (void)in_sizes; (void)n_in; (void)out_size; (void)ws_size;
    const float* x          = (const float*)d_in[0];
    const float* eps        = (const float*)d_in[3];
    const float* phi_x_W1   = (const float*)d_in[4];
    const float* phi_x_b1   = (const float*)d_in[5];
    const float* phi_x_W2   = (const float*)d_in[6];
    const float* phi_x_b2   = (const float*)d_in[7];
    const float* phi_z_W    = (const float*)d_in[8];
    const float* phi_z_b    = (const float*)d_in[9];
    const float* enc_W1     = (const float*)d_in[10];
    const float* enc_b1     = (const float*)d_in[11];
    const float* enc_W2     = (const float*)d_in[12];
    const float* enc_b2     = (const float*)d_in[13];
    const float* enc_mean_W = (const float*)d_in[14];
    const float* enc_mean_b = (const float*)d_in[15];
    const float* enc_std_W  = (const float*)d_in[16];
    const float* enc_std_b  = (const float*)d_in[17];
    const float* prior_W    = (const float*)d_in[18];
    const float* prior_b    = (const float*)d_in[19];
    const float* prior_mean_W = (const float*)d_in[20];
    const float* prior_mean_b = (const float*)d_in[21];
    const float* prior_std_W  = (const float*)d_in[22];
    const float* prior_std_b  = (const float*)d_in[23];
    const float* dec_W1     = (const float*)d_in[24];
    const float* dec_b1     = (const float*)d_in[25];
    const float* dec_W2     = (const float*)d_in[26];
    const float* dec_b2     = (const float*)d_in[27];
    const float* dec_mean_W = (const float*)d_in[28];
    const float* dec_mean_b = (const float*)d_in[29];
    const float* dec_std_W  = (const float*)d_in[30];
    const float* dec_std_b  = (const float*)d_in[31];
    const float* gru_K      = (const float*)d_in[32];
    const float* gru_R      = (const float*)d_in[33];
    const float* gru_b      = (const float*)d_in[34];

    float* out = (float*)d_out;
    char* ws = (char*)d_ws;
    f16* phix16 = (f16*)(ws + WS_PHIX16);
    f16* h16    = (f16*)(ws + WS_H16);
    f16* pz16   = (f16*)(ws + WS_PZ16);
    f16* whb    = (f16*)(ws + WS_WHB);
    f16* w1topb = (f16*)(ws + WS_W1TOP);
    f16* ktopb  = (f16*)(ws + WS_KTOP);
    f16* kbotb  = (f16*)(ws + WS_KBOT);
    f16* encw2b = (f16*)(ws + WS_ENCW2);
    f16* headsb = (f16*)(ws + WS_HEADS);
    f16* phizwb = (f16*)(ws + WS_PHIZW);
    f16* decw1T = (f16*)(ws + WS_DECW1T);
    f16* decw2T = (f16*)(ws + WS_DECW2T);
    f16* decht  = (f16*)(ws + WS_DECHT);
    f16* priwT  = (f16*)(ws + WS_PRIWT);
    f16* priht  = (f16*)(ws + WS_PRIHT);

    auto PL = [&](const float* src, f16* dst, int K, int Ns, int Nd, int off) {
        int n = K * Ns;
        pack_loop<<<(n + 255) / 256, 256, 0, stream>>>(src, dst, K, Ns, Nd, off);
    };
    auto PT = [&](const float* src, f16* dst, int K, int N, int noff, int Kd) {
        int n = K * N;
        pack_T<<<(n + 255) / 256, 256, 0, stream>>>(src, dst, K, N, noff, Kd);
    };

    // Phase 0: packing
    PL(enc_W1 + 32 * 256, whb, 256, 256, 1024, 0);    // enc_W1_bot -> Wh cols 0..255
    PL(gru_R,             whb, 256, 768, 1024, 256);  // gru_R      -> Wh cols 256..1023
    PL(enc_W1,   w1topb, 32, 256, 256, 0);
    PL(gru_K,    ktopb,  32, 768, 768, 0);
    PL(gru_K + 32 * 768, kbotb, 64, 768, 768, 0);
    PL(enc_W2,   encw2b, 256, 256, 256, 0);
    PL(enc_mean_W, headsb, 256, 64, 128, 0);
    PL(enc_std_W,  headsb, 256, 64, 128, 64);
    PL(phi_z_W,  phizwb, 64, 64, 64, 0);
    PT(dec_W1, decw1T, 320, 256, 0, 320);
    PT(dec_W2, decw2T, 256, 256, 0, 256);
    PT(dec_mean_W, decht, 256, 64, 0, 256);
    PT(dec_std_W,  decht, 256, 64, 64, 256);
    PT(prior_W, priwT, 256, 256, 0, 256);
    PT(prior_mean_W, priht, 256, 64, 0, 256);
    PT(prior_std_W,  priht, 256, 64, 64, 256);

    // Phase 1: phi_x for all B*T rows
    phi_x_kernel<<<BT_ / 256, 256, 0, stream>>>(x, phi_x_W1, phi_x_b1, phi_x_W2,
                                                phi_x_b2, out, phix16);

    // Phase 2: recurrence
    vrnn_recurrent<<<B_ / 2, 512, 0, stream>>>(
        whb, w1topb, ktopb, kbotb, encw2b, headsb, phizwb,
        enc_b1, enc_b2, enc_mean_b, enc_std_b, phi_z_b, gru_b,
        phix16, eps, h16, pz16, out);

    // Phase 3: deferred decoder + prior
    dec_kernel<<<BT_ / 32, 256, 0, stream>>>(h16, pz16, decw1T, decw2T, decht,
                                             dec_b1, dec_b2, dec_mean_b, dec_std_b, out);
    pri_kernel<<<BT_ / 32, 256, 0, stream>>>(h16, priwT, priht,
                                             prior_b, prior_mean_b, prior_std_b, out);
}